// Round 28
// baseline (53.842 us; speedup 1.0000x reference)
//
#include <hip/hip_runtime.h>
#include <hip/hip_bf16.h>

// TwinPolicy, pure-bf16 MFMA pipeline (4 launches). R26 (best, 53.2us) +
// fill rebalanced by per-kernel concurrency: prep (386 work blocks, idle-CU-
// rich) takes 33.5MB; gemm12 16.7MB; edge_z (2048 work blocks, CU-saturated,
// fill = serial tail) shrinks to 16.7MB over 512 blocks (tail ~3us, was ~11).
//   prep_all (1410): pack W1, fold Wab, bab + fill [0,33.5MB)
//   gemm12 (512 x 1024thr): fused node GEMMs (16 waves) + fill [33.5,50.3MB)
//   edge_z (2560): v[e]=exp(s[e]) + partial Z + fill [50.3,67.1MB)
//   scatter_probs (512): Z-reduce + out[src,dst]=v/Z
// R9/R21 (PERMANENT): no in-kernel grid sync on 8-XCD CDNA4.

typedef unsigned short u16;
typedef unsigned int   u32;
typedef __attribute__((ext_vector_type(8))) short bf16x8;
typedef __attribute__((ext_vector_type(4))) float f32x4;

#define N_NODES 4096
#define E_EDGES 131072
#define AS1 __attribute__((address_space(1)))
#define AS3 __attribute__((address_space(3)))

__device__ __forceinline__ u16 f2bf(float f) {
    u32 u = __float_as_uint(f);
    return (u16)((u + 0x7FFFu + ((u >> 16) & 1u)) >> 16);
}
__device__ __forceinline__ float bflo(u32 w) { return __uint_as_float(w << 16); }
__device__ __forceinline__ float bfhi(u32 w) { return __uint_as_float(w & 0xffff0000u); }

// ---------------------------------------------------------------------------
// Pack f32 [M][K] -> bf16, MFMA-ready layout.
// ---------------------------------------------------------------------------
__device__ __forceinline__ void pack_body(const float* __restrict__ in,
                                          u16* __restrict__ hi, int K, int kcs, int gid)
{
    const int r   = gid & 63;
    const int kb  = (gid >> 6) & 7;
    const int pkc = gid >> 9;
    const int kc  = pkc & ((1 << kcs) - 1);
    const int p   = pkc >> kcs;
    const size_t row = ((size_t)p << 6) | r;
    const int k0 = (kc << 6) | (kb << 3);

    const float* src = in + row * (size_t)K + k0;
    const float4 v0 = *(const float4*)src;
    const float4 v1 = *(const float4*)(src + 4);
    const float vv[8] = {v0.x, v0.y, v0.z, v0.w, v1.x, v1.y, v1.z, v1.w};

    u32 hw[4];
    #pragma unroll
    for (int q = 0; q < 4; ++q)
        hw[q] = (u32)f2bf(vv[2 * q]) | ((u32)f2bf(vv[2 * q + 1]) << 16);
    uint4 hv = {hw[0], hw[1], hw[2], hw[3]};
    *(uint4*)(hi + (size_t)gid * 8) = hv;
}

// ---------------------------------------------------------------------------
// prep_all (386 work + 1024 fill = 1410 blocks, 256 thr):
//   [0,128):    pack W1 -> w1h
//   [128,384):  fold Wab, 2 rows/block, k-vec x4
//   [384,386):  bab
//   [386,1410): fill float4 [0, 2097152): 1024 blk * 256 thr * 8
// ---------------------------------------------------------------------------
__global__ __launch_bounds__(256)
void prep_all(const float* __restrict__ W1, const float* __restrict__ We1,
              const float* __restrict__ W2, const float* __restrict__ b2,
              const float* __restrict__ be1,
              u16* __restrict__ w1h, u16* __restrict__ wabh,
              float* __restrict__ bab, float4* __restrict__ out4)
{
    const int bid = blockIdx.x;
    if (bid < 128) {
        pack_body(W1, w1h, 1024, 4, bid * 256 + threadIdx.x);
    } else if (bid < 384) {
        const int r0 = (bid - 128) * 2;
        const int c  = threadIdx.x;
        float acc0 = 0.0f, acc1 = 0.0f;
        const float* w1p = We1 + (size_t)(r0 & 255) * 512 + ((r0 >> 8) << 8);
        const int r1 = r0 + 1;
        const float* w2p = We1 + (size_t)(r1 & 255) * 512 + ((r1 >> 8) << 8);
        for (int k = 0; k < 256; k += 4) {
            const float4 a = *(const float4*)(w1p + k);
            const float4 b = *(const float4*)(w2p + k);
            const float w2a = W2[(k + 0) * 256 + c];
            const float w2b = W2[(k + 1) * 256 + c];
            const float w2c = W2[(k + 2) * 256 + c];
            const float w2d = W2[(k + 3) * 256 + c];
            acc0 += a.x * w2a; acc0 += a.y * w2b; acc0 += a.z * w2c; acc0 += a.w * w2d;
            acc1 += b.x * w2a; acc1 += b.y * w2b; acc1 += b.z * w2c; acc1 += b.w * w2d;
        }
        const int kc = c >> 6, kb = (c >> 3) & 7, e = c & 7;
        wabh[(((((size_t)(r0 >> 6) << 2) + kc) << 3) + kb) * 512 + (size_t)(r0 & 63) * 8 + e]
            = f2bf(acc0);
        wabh[(((((size_t)(r1 >> 6) << 2) + kc) << 3) + kb) * 512 + (size_t)(r1 & 63) * 8 + e]
            = f2bf(acc1);
    } else if (bid < 386) {
        const int r = (bid - 384) * 256 + threadIdx.x;
        const int i = r & 255;
        const int koff = (r >> 8) << 8;
        float acc = (r < 256) ? be1[i] : 0.0f;
        for (int k = 0; k < 256; k += 4) {
            const float4 w = *(const float4*)(We1 + (size_t)i * 512 + koff + k);
            const float4 b = *(const float4*)(b2 + k);
            acc += w.x * b.x + w.y * b.y + w.z * b.z + w.w * b.w;
        }
        bab[r] = acc;
    } else {
        const int fb = bid - 386;                 // 0..1023
        float4* op = out4 + (size_t)fb * 2048 + threadIdx.x;
        const float4 z = {0.f, 0.f, 0.f, 0.f};
        #pragma unroll
        for (int q = 0; q < 8; ++q)
            op[(size_t)q * 256] = z;
    }
}

// ---------------------------------------------------------------------------
// gemm12 (256 work + 256 fill = 512 blocks, 1024 thr):
//   blocks [0,256): 16 rows each, 16 waves (4 waves/SIMD).
//   blocks [256,512): fill float4 [2097152, 3145728): 256 blk * 1024 thr * 4
// ---------------------------------------------------------------------------
__global__ __launch_bounds__(1024)
void gemm12(const float* __restrict__ X, const u16* __restrict__ w1h,
            const u16* __restrict__ wabh, const float* __restrict__ b1,
            const float* __restrict__ bab, u16* __restrict__ ABout,
            float4* __restrict__ out4)
{
    const int b = blockIdx.x;
    if (b >= 256) {
        const int fb = b - 256;
        float4* op = out4 + 2097152 + (size_t)fb * 4096 + threadIdx.x;
        const float4 z = {0.f, 0.f, 0.f, 0.f};
        #pragma unroll
        for (int q = 0; q < 4; ++q)
            op[(size_t)q * 1024] = z;
        return;
    }

    __shared__ u16 Xp[17408];         // 128 kb-groups * 136 u16 (pad) = 34 KB
    __shared__ u16 H1[4096];          // [kb32][row16][e8] = 8 KB
    const int tid  = threadIdx.x;     // 0..1023
    const int wv   = tid >> 6;        // 0..15
    const int lane = tid & 63;
    const int kq   = lane >> 4;
    const int r16  = lane & 15;
    const int R0   = b << 4;

    // prologue: pack own 16 rows of x into Xp (coalesced reads), 2 iters
    #pragma unroll
    for (int q = 0; q < 2; ++q) {
        const int gid = (q << 10) + tid;       // 0..2047
        const int kb  = gid & 127;
        const int row = gid >> 7;
        const float* src = X + (size_t)(R0 + row) * 1024 + (kb << 3);
        const float4 v0 = *(const float4*)src;
        const float4 v1 = *(const float4*)(src + 4);
        const float vv[8] = {v0.x, v0.y, v0.z, v0.w, v1.x, v1.y, v1.z, v1.w};
        u32 hw[4];
        #pragma unroll
        for (int e = 0; e < 4; ++e)
            hw[e] = (u32)f2bf(vv[2 * e]) | ((u32)f2bf(vv[2 * e + 1]) << 16);
        uint4 hv = {hw[0], hw[1], hw[2], hw[3]};
        *(uint4*)&Xp[kb * 136 + (row << 3)] = hv;
    }
    __syncthreads();

    // phase 1: wave wv -> h1 cols [16wv, 16wv+16)
    const int pn1 = wv >> 2;                       // W1 64-col panel
    const int c01 = (wv & 3) << 4;                 // col offset within panel
    const u16* pw1 = w1h + (((size_t)pn1 * 16) << 12);

    f32x4 acc1 = (f32x4){0.f, 0.f, 0.f, 0.f};

    #pragma unroll 4
    for (int t = 0; t < 16; ++t) {
        #pragma unroll
        for (int s = 0; s < 2; ++s) {
            const int kb  = (s << 2) + kq;
            const int kbg = (t << 3) + kb;
            const bf16x8 af = *(const bf16x8*)&Xp[kbg * 136 + (r16 << 3)];
            const bf16x8 bf = *(const bf16x8*)
                (pw1 + ((size_t)t << 12) + (kb << 9) + ((size_t)(c01 + r16) << 3));
            acc1 = __builtin_amdgcn_mfma_f32_16x16x32_bf16(af, bf, acc1, 0, 0, 0);
        }
    }

    // epilogue -> H1 (phase2 A-frag layout). D: col=r16(out col), row=kq*4+j.
    {
        const int col = (wv << 4) + r16;           // h1 col 0..255
        const float bv = b1[col];
        const int kb2 = col >> 3;
        #pragma unroll
        for (int j = 0; j < 4; ++j) {
            const float v = fmaxf(acc1[j] + bv, 0.0f);
            H1[(((kb2 << 4) + (kq << 2) + j) << 3) + (col & 7)] = f2bf(v);
        }
    }
    __syncthreads();

    // phase 2: wave wv -> AB cols [32wv, 32wv+32)
    const u16* pw2 = wabh + (((size_t)(wv >> 1) * 4) << 12);
    f32x4 acc2[2];
    acc2[0] = (f32x4){0.f, 0.f, 0.f, 0.f};
    acc2[1] = (f32x4){0.f, 0.f, 0.f, 0.f};

    #pragma unroll
    for (int t = 0; t < 4; ++t) {
        #pragma unroll
        for (int s = 0; s < 2; ++s) {
            const int kb = (s << 2) + kq;
            const int kb32 = (t << 3) + kb;
            const bf16x8 af = *(const bf16x8*)&H1[((kb32 << 4) + r16) << 3];
            #pragma unroll
            for (int n = 0; n < 2; ++n) {
                const int c0 = ((wv & 1) << 5) + (n << 4);     // within 64-col panel
                const bf16x8 bf = *(const bf16x8*)
                    (pw2 + ((size_t)t << 12) + (kb << 9) + ((size_t)(c0 + r16) << 3));
                acc2[n] = __builtin_amdgcn_mfma_f32_16x16x32_bf16(af, bf, acc2[n], 0, 0, 0);
            }
        }
    }

    #pragma unroll
    for (int n = 0; n < 2; ++n) {
        const int col = (wv << 5) + (n << 4) + r16;    // 0..511
        const float bv = bab[col];
        #pragma unroll
        for (int j = 0; j < 4; ++j) {
            const int row = R0 + (kq << 2) + j;
            ABout[(size_t)row * 512 + col] = f2bf(acc2[n][j] + bv);
        }
    }
}

// ---------------------------------------------------------------------------
// edge_z (2048 edge + 512 fill = 2560 blocks, 256 thr):
//   blocks [0,2048):    v[e]=exp(s[e]) + block partial Z
//   blocks [2048,2560): fill float4 [3145728, 4194304): 512 blk * 256 thr * 8
// ---------------------------------------------------------------------------
__global__ __launch_bounds__(256)
void edge_z(const u16* __restrict__ AB, const int* __restrict__ idx,
            const float* __restrict__ We2, const float* __restrict__ be2p,
            float* __restrict__ vbuf, float* __restrict__ part,
            float4* __restrict__ out4)
{
    const int bid = blockIdx.x;
    const int tid = threadIdx.x;

    if (bid >= 2048) {
        const int fb = bid - 2048;                // 0..511
        float4* op = out4 + 3145728 + (size_t)fb * 2048 + tid;
        const float4 z = {0.f, 0.f, 0.f, 0.f};
        #pragma unroll
        for (int q = 0; q < 8; ++q)
            op[(size_t)q * 256] = z;
        return;
    }

    __shared__ float sm[256];
    const int cb   = bid;
    const int lane = tid & 63;
    const int sub  = lane >> 5;
    const int l5   = lane & 31;
    const int wid  = (cb * 256 + tid) >> 6;
    const float be2 = be2p[0];

    float w2v[8];
    #pragma unroll
    for (int q = 0; q < 2; ++q) {
        const float4 w = ((const float4*)We2)[l5 * 2 + q];
        w2v[q * 4 + 0] = w.x; w2v[q * 4 + 1] = w.y;
        w2v[q * 4 + 2] = w.z; w2v[q * 4 + 3] = w.w;
    }

    float zloc = 0.0f;
    #pragma unroll
    for (int it = 0; it < 8; ++it) {
        const int e = (wid << 1) + sub + (it << 14);    // covers [0, 131072)
        const int src = idx[2 * e];
        const int dst = idx[2 * e + 1];
        const uint4 av = *(const uint4*)(AB + ((size_t)src << 9) + (l5 << 3));
        const uint4 bv = *(const uint4*)(AB + ((size_t)dst << 9) + 256 + (l5 << 3));
        const u32 aw[4] = {av.x, av.y, av.z, av.w};
        const u32 bw[4] = {bv.x, bv.y, bv.z, bv.w};
        float p = 0.0f;
        #pragma unroll
        for (int q = 0; q < 4; ++q) {
            p += fmaxf(bflo(aw[q]) + bflo(bw[q]), 0.0f) * w2v[2 * q];
            p += fmaxf(bfhi(aw[q]) + bfhi(bw[q]), 0.0f) * w2v[2 * q + 1];
        }
        #pragma unroll
        for (int m = 16; m > 0; m >>= 1)
            p += __shfl_xor(p, m, 64);   // xor<32: stays within the half-wave
        const float v = expf(p + be2);
        if (l5 == 0) {
            vbuf[e] = v;
            zloc += v;
        }
    }
    sm[tid] = zloc;
    __syncthreads();
    for (int st = 128; st > 0; st >>= 1) {
        if (tid < st) sm[tid] += sm[tid + st];
        __syncthreads();
    }
    if (tid == 0) part[cb] = sm[0];
}

// fused: finalize Z over part[2048] (redundant per block) + scatter probs
__global__ __launch_bounds__(256)
void scatter_probs(const float* __restrict__ vbuf, const int* __restrict__ idx,
                   const float* __restrict__ part, float* __restrict__ out, int n)
{
    __shared__ float sm[256];
    float a = part[threadIdx.x];
    #pragma unroll
    for (int k = 1; k < 8; ++k)
        a += part[threadIdx.x + k * 256];
    sm[threadIdx.x] = a;
    __syncthreads();
    for (int st = 128; st > 0; st >>= 1) {
        if (threadIdx.x < st) sm[threadIdx.x] += sm[threadIdx.x + st];
        __syncthreads();
    }
    const float Z = sm[0];
    const int e = blockIdx.x * 256 + threadIdx.x;
    if (e < n)
        out[(size_t)idx[2 * e] * N_NODES + idx[2 * e + 1]] = vbuf[e] / Z;
}

// ---------------------------------------------------------------------------
extern "C" void kernel_launch(void* const* d_in, const int* in_sizes, int n_in,
                              void* d_out, int out_size, void* d_ws, size_t ws_size,
                              hipStream_t stream)
{
    const float* ideal = (const float*)d_in[0];   // 4096 x 1024
    const int*   idx   = (const int*)d_in[1];     // E x 2
    const float* W1    = (const float*)d_in[2];   // 256 x 1024
    const float* b1    = (const float*)d_in[3];   // 256
    const float* W2    = (const float*)d_in[4];   // 256 x 256
    const float* b2    = (const float*)d_in[5];   // 256
    const float* We1   = (const float*)d_in[6];   // 256 x 512
    const float* be1   = (const float*)d_in[7];   // 256
    const float* We2   = (const float*)d_in[8];   // 256
    const float* be2   = (const float*)d_in[9];   // 1
    float* out = (float*)d_out;

    char* Wb = (char*)d_ws;
    u16*   w1h  = (u16*)(Wb);                          // 512 KB packed W1
    u16*   wabh = (u16*)(Wb + (512u << 10));           // 256 KB packed Wab
    float* bab  = (float*)(Wb + (768u << 10));         // 2 KB
    u16*   ABbf = (u16*)(Wb + (1u << 20));             // 4 MB bf16 AB row-major
    float* vbuf = (float*)(Wb + (6u << 20));           // 512 KB exp(scores)
    float* part = vbuf + E_EDGES;                      // 2048 partial Z

    // weight prep (+ 33.5MB fill over 1024 blocks, concurrent with work)
    prep_all<<<1410, 256, 0, stream>>>(W1, We1, W2, b2, be1,
                                       w1h, wabh, bab, (float4*)out);

    // fused node pipeline, 16 waves/block (+ 16.7MB fill)
    gemm12<<<512, 1024, 0, stream>>>(ideal, w1h, wabh, b1, bab, ABbf, (float4*)out);

    // edge scores + partial Z (+ 16.7MB fill over 512 blocks, short tail)
    edge_z<<<2560, 256, 0, stream>>>(ABbf, idx, We2, be2, vbuf, part, (float4*)out);
    // Z finalize (redundant per block) + scatter
    scatter_probs<<<512, 256, 0, stream>>>(vbuf, idx, part, out, E_EDGES);
}

// Round 29
// 52.979 us; speedup vs baseline: 1.0163x; 1.0163x over previous
//
#include <hip/hip_runtime.h>
#include <hip/hip_bf16.h>

// TwinPolicy, pure-bf16 MFMA pipeline (4 launches) — FINAL (R26 config,
// best measured 53.2us; R27/R28 fill-topology tweaks were within-noise
// negative and are reverted).
//   prep_all (514):  pack W1, fold Wab (4x-parallel), bab + fill shard 0
//   gemm12 (512 x 1024thr): row-local fused node GEMMs (16 waves = 4/SIMD)
//                           + fill shards 1,2
//   edge_z (2176):   v[e]=exp(s[e]) + partial Z + fill shard 3
//   scatter_probs (512): Z-reduce + out[src,dst]=v/Z
// Session lessons baked in:
//  - R9/R21: NO in-kernel grid sync on 8-XCD CDNA4 (acq_rel flushes / spin
//    serialization lose to stream ordering by 3-5x). PERMANENT.
//  - R15/R22 diagnostics: latency-bound phases fixed by TLP (many blocks,
//    many waves/SIMD), not by pipelining tricks.
//  - R12: keep f32->bf16 conversion OUT of GEMM K-loops (prologue-only).
//  - Algebra: concat-GEMM split (We1 = [We1a|We1b]) + W2 folded into edge
//    weights; softmax max-subtraction dropped (|s|=O(1)); exp/Z in f32.

typedef unsigned short u16;
typedef unsigned int   u32;
typedef __attribute__((ext_vector_type(8))) short bf16x8;
typedef __attribute__((ext_vector_type(4))) float f32x4;

#define N_NODES 4096
#define E_EDGES 131072
#define AS1 __attribute__((address_space(1)))
#define AS3 __attribute__((address_space(3)))

__device__ __forceinline__ u16 f2bf(float f) {
    u32 u = __float_as_uint(f);
    return (u16)((u + 0x7FFFu + ((u >> 16) & 1u)) >> 16);
}
__device__ __forceinline__ float bflo(u32 w) { return __uint_as_float(w << 16); }
__device__ __forceinline__ float bfhi(u32 w) { return __uint_as_float(w & 0xffff0000u); }

// fill shard s, block fb (of 128), 256-thr: 128*256*32 float4 = 16.77MB
__device__ __forceinline__ void fill_shard(float4* __restrict__ out4,
                                           int shard, int fb, int tid)
{
    float4* op = out4 + (size_t)shard * 1048576 + (size_t)fb * 8192 + tid;
    const float4 z = {0.f, 0.f, 0.f, 0.f};
    #pragma unroll 8
    for (int q = 0; q < 32; ++q)
        op[(size_t)q * 256] = z;
}

// ---------------------------------------------------------------------------
// Pack f32 [M][K] -> bf16, MFMA-ready layout.
// ---------------------------------------------------------------------------
__device__ __forceinline__ void pack_body(const float* __restrict__ in,
                                          u16* __restrict__ hi, int K, int kcs, int gid)
{
    const int r   = gid & 63;
    const int kb  = (gid >> 6) & 7;
    const int pkc = gid >> 9;
    const int kc  = pkc & ((1 << kcs) - 1);
    const int p   = pkc >> kcs;
    const size_t row = ((size_t)p << 6) | r;
    const int k0 = (kc << 6) | (kb << 3);

    const float* src = in + row * (size_t)K + k0;
    const float4 v0 = *(const float4*)src;
    const float4 v1 = *(const float4*)(src + 4);
    const float vv[8] = {v0.x, v0.y, v0.z, v0.w, v1.x, v1.y, v1.z, v1.w};

    u32 hw[4];
    #pragma unroll
    for (int q = 0; q < 4; ++q)
        hw[q] = (u32)f2bf(vv[2 * q]) | ((u32)f2bf(vv[2 * q + 1]) << 16);
    uint4 hv = {hw[0], hw[1], hw[2], hw[3]};
    *(uint4*)(hi + (size_t)gid * 8) = hv;
}

// ---------------------------------------------------------------------------
// prep_all (386 work + 128 fill = 514 blocks, 256 thr)
// ---------------------------------------------------------------------------
__global__ __launch_bounds__(256)
void prep_all(const float* __restrict__ W1, const float* __restrict__ We1,
              const float* __restrict__ W2, const float* __restrict__ b2,
              const float* __restrict__ be1,
              u16* __restrict__ w1h, u16* __restrict__ wabh,
              float* __restrict__ bab, float4* __restrict__ out4)
{
    const int bid = blockIdx.x;
    if (bid < 128) {
        pack_body(W1, w1h, 1024, 4, bid * 256 + threadIdx.x);
    } else if (bid < 384) {
        const int r0 = (bid - 128) * 2;
        const int c  = threadIdx.x;
        float acc0 = 0.0f, acc1 = 0.0f;
        const float* w1p = We1 + (size_t)(r0 & 255) * 512 + ((r0 >> 8) << 8);
        const int r1 = r0 + 1;
        const float* w2p = We1 + (size_t)(r1 & 255) * 512 + ((r1 >> 8) << 8);
        for (int k = 0; k < 256; k += 4) {
            const float4 a = *(const float4*)(w1p + k);
            const float4 b = *(const float4*)(w2p + k);
            const float w2a = W2[(k + 0) * 256 + c];
            const float w2b = W2[(k + 1) * 256 + c];
            const float w2c = W2[(k + 2) * 256 + c];
            const float w2d = W2[(k + 3) * 256 + c];
            acc0 += a.x * w2a; acc0 += a.y * w2b; acc0 += a.z * w2c; acc0 += a.w * w2d;
            acc1 += b.x * w2a; acc1 += b.y * w2b; acc1 += b.z * w2c; acc1 += b.w * w2d;
        }
        const int kc = c >> 6, kb = (c >> 3) & 7, e = c & 7;
        wabh[(((((size_t)(r0 >> 6) << 2) + kc) << 3) + kb) * 512 + (size_t)(r0 & 63) * 8 + e]
            = f2bf(acc0);
        wabh[(((((size_t)(r1 >> 6) << 2) + kc) << 3) + kb) * 512 + (size_t)(r1 & 63) * 8 + e]
            = f2bf(acc1);
    } else if (bid < 386) {
        const int r = (bid - 384) * 256 + threadIdx.x;
        const int i = r & 255;
        const int koff = (r >> 8) << 8;
        float acc = (r < 256) ? be1[i] : 0.0f;
        for (int k = 0; k < 256; k += 4) {
            const float4 w = *(const float4*)(We1 + (size_t)i * 512 + koff + k);
            const float4 b = *(const float4*)(b2 + k);
            acc += w.x * b.x + w.y * b.y + w.z * b.z + w.w * b.w;
        }
        bab[r] = acc;
    } else {
        fill_shard(out4, 0, bid - 386, threadIdx.x);
    }
}

// ---------------------------------------------------------------------------
// gemm12 (256 work + 256 fill = 512 blocks, 1024 thr):
//   blocks [0,256): 16 rows each, 16 waves (4 waves/SIMD).
//     prologue: pack own 16 rows of x -> Xp LDS (cvt once, coalesced).
//     phase1: wave w -> h1 cols [16w,16w+16), K=1024; A from Xp, W1 frags
//             direct global (packed). epilogue relu+b1 -> H1 LDS.
//     phase2: wave w -> AB cols [32w,32w+32), K=256; Wab frags L2-hot.
//   blocks [256,512): fill shards 1+2 (1024 thr x 8 float4 = 33.5MB total).
// ---------------------------------------------------------------------------
__global__ __launch_bounds__(1024)
void gemm12(const float* __restrict__ X, const u16* __restrict__ w1h,
            const u16* __restrict__ wabh, const float* __restrict__ b1,
            const float* __restrict__ bab, u16* __restrict__ ABout,
            float4* __restrict__ out4)
{
    const int b = blockIdx.x;
    if (b >= 256) {
        // fill shards 1+2: float4 region [1048576, 3145728)
        const int fb = b - 256;
        float4* op = out4 + 1048576 + (size_t)fb * 8192 + threadIdx.x;
        const float4 z = {0.f, 0.f, 0.f, 0.f};
        #pragma unroll
        for (int q = 0; q < 8; ++q)
            op[(size_t)q * 1024] = z;
        return;
    }

    __shared__ u16 Xp[17408];         // 128 kb-groups * 136 u16 (pad) = 34 KB
    __shared__ u16 H1[4096];          // [kb32][row16][e8] = 8 KB
    const int tid  = threadIdx.x;     // 0..1023
    const int wv   = tid >> 6;        // 0..15
    const int lane = tid & 63;
    const int kq   = lane >> 4;
    const int r16  = lane & 15;
    const int R0   = b << 4;

    // prologue: pack own 16 rows of x into Xp (coalesced reads), 2 iters
    #pragma unroll
    for (int q = 0; q < 2; ++q) {
        const int gid = (q << 10) + tid;       // 0..2047
        const int kb  = gid & 127;
        const int row = gid >> 7;
        const float* src = X + (size_t)(R0 + row) * 1024 + (kb << 3);
        const float4 v0 = *(const float4*)src;
        const float4 v1 = *(const float4*)(src + 4);
        const float vv[8] = {v0.x, v0.y, v0.z, v0.w, v1.x, v1.y, v1.z, v1.w};
        u32 hw[4];
        #pragma unroll
        for (int e = 0; e < 4; ++e)
            hw[e] = (u32)f2bf(vv[2 * e]) | ((u32)f2bf(vv[2 * e + 1]) << 16);
        uint4 hv = {hw[0], hw[1], hw[2], hw[3]};
        *(uint4*)&Xp[kb * 136 + (row << 3)] = hv;
    }
    __syncthreads();

    // phase 1: wave wv -> h1 cols [16wv, 16wv+16)
    const int pn1 = wv >> 2;                       // W1 64-col panel
    const int c01 = (wv & 3) << 4;                 // col offset within panel
    const u16* pw1 = w1h + (((size_t)pn1 * 16) << 12);

    f32x4 acc1 = (f32x4){0.f, 0.f, 0.f, 0.f};

    #pragma unroll 4
    for (int t = 0; t < 16; ++t) {
        #pragma unroll
        for (int s = 0; s < 2; ++s) {
            const int kb  = (s << 2) + kq;
            const int kbg = (t << 3) + kb;
            const bf16x8 af = *(const bf16x8*)&Xp[kbg * 136 + (r16 << 3)];
            const bf16x8 bf = *(const bf16x8*)
                (pw1 + ((size_t)t << 12) + (kb << 9) + ((size_t)(c01 + r16) << 3));
            acc1 = __builtin_amdgcn_mfma_f32_16x16x32_bf16(af, bf, acc1, 0, 0, 0);
        }
    }

    // epilogue -> H1 (phase2 A-frag layout). D: col=r16(out col), row=kq*4+j.
    {
        const int col = (wv << 4) + r16;           // h1 col 0..255
        const float bv = b1[col];
        const int kb2 = col >> 3;
        #pragma unroll
        for (int j = 0; j < 4; ++j) {
            const float v = fmaxf(acc1[j] + bv, 0.0f);
            H1[(((kb2 << 4) + (kq << 2) + j) << 3) + (col & 7)] = f2bf(v);
        }
    }
    __syncthreads();

    // phase 2: wave wv -> AB cols [32wv, 32wv+32)
    const u16* pw2 = wabh + (((size_t)(wv >> 1) * 4) << 12);
    f32x4 acc2[2];
    acc2[0] = (f32x4){0.f, 0.f, 0.f, 0.f};
    acc2[1] = (f32x4){0.f, 0.f, 0.f, 0.f};

    #pragma unroll
    for (int t = 0; t < 4; ++t) {
        #pragma unroll
        for (int s = 0; s < 2; ++s) {
            const int kb = (s << 2) + kq;
            const int kb32 = (t << 3) + kb;
            const bf16x8 af = *(const bf16x8*)&H1[((kb32 << 4) + r16) << 3];
            #pragma unroll
            for (int n = 0; n < 2; ++n) {
                const int c0 = ((wv & 1) << 5) + (n << 4);     // within 64-col panel
                const bf16x8 bf = *(const bf16x8*)
                    (pw2 + ((size_t)t << 12) + (kb << 9) + ((size_t)(c0 + r16) << 3));
                acc2[n] = __builtin_amdgcn_mfma_f32_16x16x32_bf16(af, bf, acc2[n], 0, 0, 0);
            }
        }
    }

    #pragma unroll
    for (int n = 0; n < 2; ++n) {
        const int col = (wv << 5) + (n << 4) + r16;    // 0..511
        const float bv = bab[col];
        #pragma unroll
        for (int j = 0; j < 4; ++j) {
            const int row = R0 + (kq << 2) + j;
            ABout[(size_t)row * 512 + col] = f2bf(acc2[n][j] + bv);
        }
    }
}

// ---------------------------------------------------------------------------
// edge_z (2048 edge + 128 fill = 2176 blocks, 256 thr)
// ---------------------------------------------------------------------------
__global__ __launch_bounds__(256)
void edge_z(const u16* __restrict__ AB, const int* __restrict__ idx,
            const float* __restrict__ We2, const float* __restrict__ be2p,
            float* __restrict__ vbuf, float* __restrict__ part,
            float4* __restrict__ out4)
{
    const int bid = blockIdx.x;
    const int tid = threadIdx.x;

    if (bid >= 2048) {
        fill_shard(out4, 3, bid - 2048, tid);
        return;
    }

    __shared__ float sm[256];
    const int cb   = bid;
    const int lane = tid & 63;
    const int sub  = lane >> 5;
    const int l5   = lane & 31;
    const int wid  = (cb * 256 + tid) >> 6;
    const float be2 = be2p[0];

    float w2v[8];
    #pragma unroll
    for (int q = 0; q < 2; ++q) {
        const float4 w = ((const float4*)We2)[l5 * 2 + q];
        w2v[q * 4 + 0] = w.x; w2v[q * 4 + 1] = w.y;
        w2v[q * 4 + 2] = w.z; w2v[q * 4 + 3] = w.w;
    }

    float zloc = 0.0f;
    #pragma unroll
    for (int it = 0; it < 8; ++it) {
        const int e = (wid << 1) + sub + (it << 14);    // covers [0, 131072)
        const int src = idx[2 * e];
        const int dst = idx[2 * e + 1];
        const uint4 av = *(const uint4*)(AB + ((size_t)src << 9) + (l5 << 3));
        const uint4 bv = *(const uint4*)(AB + ((size_t)dst << 9) + 256 + (l5 << 3));
        const u32 aw[4] = {av.x, av.y, av.z, av.w};
        const u32 bw[4] = {bv.x, bv.y, bv.z, bv.w};
        float p = 0.0f;
        #pragma unroll
        for (int q = 0; q < 4; ++q) {
            p += fmaxf(bflo(aw[q]) + bflo(bw[q]), 0.0f) * w2v[2 * q];
            p += fmaxf(bfhi(aw[q]) + bfhi(bw[q]), 0.0f) * w2v[2 * q + 1];
        }
        #pragma unroll
        for (int m = 16; m > 0; m >>= 1)
            p += __shfl_xor(p, m, 64);   // xor<32: stays within the half-wave
        const float v = expf(p + be2);
        if (l5 == 0) {
            vbuf[e] = v;
            zloc += v;
        }
    }
    sm[tid] = zloc;
    __syncthreads();
    for (int st = 128; st > 0; st >>= 1) {
        if (tid < st) sm[tid] += sm[tid + st];
        __syncthreads();
    }
    if (tid == 0) part[cb] = sm[0];
}

// fused: finalize Z over part[2048] (redundant per block) + scatter probs
__global__ __launch_bounds__(256)
void scatter_probs(const float* __restrict__ vbuf, const int* __restrict__ idx,
                   const float* __restrict__ part, float* __restrict__ out, int n)
{
    __shared__ float sm[256];
    float a = part[threadIdx.x];
    #pragma unroll
    for (int k = 1; k < 8; ++k)
        a += part[threadIdx.x + k * 256];
    sm[threadIdx.x] = a;
    __syncthreads();
    for (int st = 128; st > 0; st >>= 1) {
        if (threadIdx.x < st) sm[threadIdx.x] += sm[threadIdx.x + st];
        __syncthreads();
    }
    const float Z = sm[0];
    const int e = blockIdx.x * 256 + threadIdx.x;
    if (e < n)
        out[(size_t)idx[2 * e] * N_NODES + idx[2 * e + 1]] = vbuf[e] / Z;
}

// ---------------------------------------------------------------------------
extern "C" void kernel_launch(void* const* d_in, const int* in_sizes, int n_in,
                              void* d_out, int out_size, void* d_ws, size_t ws_size,
                              hipStream_t stream)
{
    const float* ideal = (const float*)d_in[0];   // 4096 x 1024
    const int*   idx   = (const int*)d_in[1];     // E x 2
    const float* W1    = (const float*)d_in[2];   // 256 x 1024
    const float* b1    = (const float*)d_in[3];   // 256
    const float* W2    = (const float*)d_in[4];   // 256 x 256
    const float* b2    = (const float*)d_in[5];   // 256
    const float* We1   = (const float*)d_in[6];   // 256 x 512
    const float* be1   = (const float*)d_in[7];   // 256
    const float* We2   = (const float*)d_in[8];   // 256
    const float* be2   = (const float*)d_in[9];   // 1
    float* out = (float*)d_out;

    char* Wb = (char*)d_ws;
    u16*   w1h  = (u16*)(Wb);                          // 512 KB packed W1
    u16*   wabh = (u16*)(Wb + (512u << 10));           // 256 KB packed Wab
    float* bab  = (float*)(Wb + (768u << 10));         // 2 KB
    u16*   ABbf = (u16*)(Wb + (1u << 20));             // 4 MB bf16 AB row-major
    float* vbuf = (float*)(Wb + (6u << 20));           // 512 KB exp(scores)
    float* part = vbuf + E_EDGES;                      // 2048 partial Z

    // weight prep (+ fill shard 0)
    prep_all<<<514, 256, 0, stream>>>(W1, We1, W2, b2, be1,
                                      w1h, wabh, bab, (float4*)out);

    // fused node pipeline, 16 waves/block (+ fill shards 1,2)
    gemm12<<<512, 1024, 0, stream>>>(ideal, w1h, wabh, b1, bab, ABbf, (float4*)out);

    // edge scores + partial Z (+ fill shard 3)
    edge_z<<<2176, 256, 0, stream>>>(ABbf, idx, We2, be2, vbuf, part, (float4*)out);
    // Z finalize (redundant per block) + scatter
    scatter_probs<<<512, 256, 0, stream>>>(vbuf, idx, part, out, E_EDGES);
}